// Round 1
// baseline (32.918 us; speedup 1.0000x reference)
//
#include <hip/hip_runtime.h>

// GradedRelevanceLoss: out = mse + 0.1 * ranking_loss
//   mse = mean((p-t)^2), n = 8192
//   ranking = sum over ordered pairs (a,b) with t_a > t_b of max(0, 0.1 - (p_a - p_b)),
//             divided by count of such pairs.
// Equivalent to the reference's i<j unordered-pair formulation (each non-tied
// unordered pair contributes exactly once, with a = the larger-target element).

constexpr int N = 8192;
constexpr int BLK = 256;
constexpr int NB = N / BLK;       // 32 tiles per dimension
constexpr int NBLOCKS = NB * NB;  // 1024
#define MARGIN_F 0.1f
#define RANK_WEIGHT 0.1

__device__ __forceinline__ float wave_reduce_f(float v) {
    #pragma unroll
    for (int off = 32; off > 0; off >>= 1) v += __shfl_down(v, off, 64);
    return v;
}
__device__ __forceinline__ unsigned int wave_reduce_u(unsigned int v) {
    #pragma unroll
    for (int off = 32; off > 0; off >>= 1) v += __shfl_down(v, off, 64);
    return v;
}

__global__ __launch_bounds__(BLK) void pair_kernel(
    const float* __restrict__ pred, const float* __restrict__ targ,
    float* __restrict__ rank_partial, unsigned int* __restrict__ cnt_partial)
{
    __shared__ float2 tp[BLK];        // (targ, pred) for the j-tile
    __shared__ float red_s[4];
    __shared__ unsigned int red_c[4];

    const int blk = blockIdx.x;
    const int bi = blk >> 5;          // blk / 32
    const int bj = blk & 31;          // blk % 32
    const int tid = threadIdx.x;
    const int i = bi * BLK + tid;
    const int j0 = bj * BLK;

    tp[tid] = make_float2(targ[j0 + tid], pred[j0 + tid]);
    const float ti = targ[i];
    const float a = MARGIN_F - pred[i];   // hinge = max(0, a + p_b)
    __syncthreads();

    float s = 0.0f;
    unsigned int c = 0u;
    #pragma unroll 8
    for (int j = 0; j < BLK; ++j) {
        float2 v = tp[j];             // broadcast read (same addr all lanes)
        if (ti > v.x) {               // t_a > t_b: this ordered pair counts
            s += fmaxf(0.0f, a + v.y);
            c += 1u;
        }
    }

    s = wave_reduce_f(s);
    c = wave_reduce_u(c);
    const int wave = tid >> 6, lane = tid & 63;
    if (lane == 0) { red_s[wave] = s; red_c[wave] = c; }
    __syncthreads();
    if (tid == 0) {
        rank_partial[blk] = red_s[0] + red_s[1] + red_s[2] + red_s[3];
        cnt_partial[blk]  = red_c[0] + red_c[1] + red_c[2] + red_c[3];
    }
}

__global__ __launch_bounds__(BLK) void finalize_kernel(
    const float* __restrict__ pred, const float* __restrict__ targ,
    const float* __restrict__ rank_partial,
    const unsigned int* __restrict__ cnt_partial,
    float* __restrict__ out)
{
    __shared__ double red_d[4];
    __shared__ unsigned long long red_u[4];
    __shared__ double red_m[4];
    const int tid = threadIdx.x;

    double rs = 0.0;
    unsigned long long cc = 0ull;
    for (int k = tid; k < NBLOCKS; k += BLK) {
        rs += (double)rank_partial[k];
        cc += (unsigned long long)cnt_partial[k];
    }
    float ms = 0.0f;
    for (int k = tid; k < N; k += BLK) {
        float d = pred[k] - targ[k];
        ms = fmaf(d, d, ms);
    }
    double msd = (double)ms;

    #pragma unroll
    for (int off = 32; off > 0; off >>= 1) {
        rs  += __shfl_down(rs, off, 64);
        msd += __shfl_down(msd, off, 64);
        cc  += __shfl_down(cc, off, 64);
    }
    const int wave = tid >> 6, lane = tid & 63;
    if (lane == 0) { red_d[wave] = rs; red_u[wave] = cc; red_m[wave] = msd; }
    __syncthreads();
    if (tid == 0) {
        double rsum = red_d[0] + red_d[1] + red_d[2] + red_d[3];
        unsigned long long ct = red_u[0] + red_u[1] + red_u[2] + red_u[3];
        double mse = (red_m[0] + red_m[1] + red_m[2] + red_m[3]) / (double)N;
        double rank = (ct > 0ull) ? rsum / (double)ct : 0.0;
        out[0] = (float)(mse + RANK_WEIGHT * rank);
    }
}

extern "C" void kernel_launch(void* const* d_in, const int* in_sizes, int n_in,
                              void* d_out, int out_size, void* d_ws, size_t ws_size,
                              hipStream_t stream) {
    const float* pred = (const float*)d_in[0];
    const float* targ = (const float*)d_in[1];
    float* rank_partial = (float*)d_ws;
    unsigned int* cnt_partial = (unsigned int*)((char*)d_ws + NBLOCKS * sizeof(float));

    pair_kernel<<<NBLOCKS, BLK, 0, stream>>>(pred, targ, rank_partial, cnt_partial);
    finalize_kernel<<<1, BLK, 0, stream>>>(pred, targ, rank_partial, cnt_partial,
                                           (float*)d_out);
}

// Round 2
// 22.955 us; speedup vs baseline: 1.4340x; 1.4340x over previous
//
#include <hip/hip_runtime.h>

// GradedRelevanceLoss: out = mse + 0.1 * ranking_loss
//   mse = mean((p-t)^2), n = 8192
//   ranking = sum over ordered pairs (a,b) with t_a > t_b of max(0, 0.1 - (p_a - p_b)),
//             divided by count of such pairs. Each non-tied unordered pair contributes
//             exactly once (the direction with the larger target), matching the
//             reference's i<j masked formulation. Ties excluded from sum AND count.

constexpr int N = 8192;
constexpr int BLK = 256;
constexpr int NB = N / BLK;       // 32 tiles per dimension
constexpr int NBLOCKS = NB * NB;  // 1024
#define MARGIN_F 0.1f
#define RANK_WEIGHT 0.1

__device__ __forceinline__ float wave_reduce_f(float v) {
    #pragma unroll
    for (int off = 32; off > 0; off >>= 1) v += __shfl_down(v, off, 64);
    return v;
}
__device__ __forceinline__ unsigned int wave_reduce_u(unsigned int v) {
    #pragma unroll
    for (int off = 32; off > 0; off >>= 1) v += __shfl_down(v, off, 64);
    return v;
}

__global__ __launch_bounds__(BLK) void pair_kernel(
    const float* __restrict__ pred, const float* __restrict__ targ,
    float* __restrict__ rank_partial, unsigned int* __restrict__ cnt_partial,
    float* __restrict__ mse_partial)
{
    // j-tile staged as (t0,p0,t1,p1) float4s -> one ds_read_b128 covers 2 pairs
    __shared__ float4 tp4[BLK / 2];
    __shared__ float red_s[4];
    __shared__ unsigned int red_c[4];
    __shared__ float red_m[4];

    const int blk = blockIdx.x;
    const int bi = blk >> 5;          // blk / 32
    const int bj = blk & 31;          // blk % 32
    const int tid = threadIdx.x;
    const int i = bi * BLK + tid;
    const int j0 = bj * BLK;

    float2* tp2 = reinterpret_cast<float2*>(tp4);
    tp2[tid] = make_float2(targ[j0 + tid], pred[j0 + tid]);
    const float ti = targ[i];
    const float pi = pred[i];
    const float a = MARGIN_F - pi;    // hinge = max(0, a + p_b)
    __syncthreads();

    float s = 0.0f;
    unsigned int c = 0u;
    #pragma unroll 16
    for (int j = 0; j < BLK / 2; ++j) {
        float4 v = tp4[j];            // broadcast read (same addr all lanes)
        const bool c0 = ti > v.x;
        const bool c1 = ti > v.z;
        s += c0 ? fmaxf(0.0f, a + v.y) : 0.0f;
        s += c1 ? fmaxf(0.0f, a + v.w) : 0.0f;
        c += (unsigned int)c0;
        c += (unsigned int)c1;
    }

    // diagonal blocks also produce the MSE partial for their i-range
    float m = 0.0f;
    if (bi == bj) {
        const float d = pi - ti;
        m = d * d;
    }

    s = wave_reduce_f(s);
    c = wave_reduce_u(c);
    m = wave_reduce_f(m);
    const int wave = tid >> 6, lane = tid & 63;
    if (lane == 0) { red_s[wave] = s; red_c[wave] = c; red_m[wave] = m; }
    __syncthreads();
    if (tid == 0) {
        rank_partial[blk] = red_s[0] + red_s[1] + red_s[2] + red_s[3];
        cnt_partial[blk]  = red_c[0] + red_c[1] + red_c[2] + red_c[3];
        if (bi == bj) mse_partial[bi] = red_m[0] + red_m[1] + red_m[2] + red_m[3];
    }
}

__global__ __launch_bounds__(BLK) void finalize_kernel(
    const float* __restrict__ rank_partial,
    const unsigned int* __restrict__ cnt_partial,
    const float* __restrict__ mse_partial,
    float* __restrict__ out)
{
    __shared__ double red_d[4];
    __shared__ unsigned long long red_u[4];
    __shared__ double red_m[4];
    const int tid = threadIdx.x;

    double rs = 0.0;
    unsigned long long cc = 0ull;
    #pragma unroll
    for (int k = tid; k < NBLOCKS; k += BLK) {
        rs += (double)rank_partial[k];
        cc += (unsigned long long)cnt_partial[k];
    }
    double msd = (tid < NB) ? (double)mse_partial[tid] : 0.0;

    #pragma unroll
    for (int off = 32; off > 0; off >>= 1) {
        rs  += __shfl_down(rs, off, 64);
        msd += __shfl_down(msd, off, 64);
        cc  += __shfl_down(cc, off, 64);
    }
    const int wave = tid >> 6, lane = tid & 63;
    if (lane == 0) { red_d[wave] = rs; red_u[wave] = cc; red_m[wave] = msd; }
    __syncthreads();
    if (tid == 0) {
        double rsum = red_d[0] + red_d[1] + red_d[2] + red_d[3];
        unsigned long long ct = red_u[0] + red_u[1] + red_u[2] + red_u[3];
        double mse = (red_m[0] + red_m[1] + red_m[2] + red_m[3]) / (double)N;
        double rank = (ct > 0ull) ? rsum / (double)ct : 0.0;
        out[0] = (float)(mse + RANK_WEIGHT * rank);
    }
}

extern "C" void kernel_launch(void* const* d_in, const int* in_sizes, int n_in,
                              void* d_out, int out_size, void* d_ws, size_t ws_size,
                              hipStream_t stream) {
    const float* pred = (const float*)d_in[0];
    const float* targ = (const float*)d_in[1];
    float* rank_partial = (float*)d_ws;
    unsigned int* cnt_partial = (unsigned int*)((char*)d_ws + NBLOCKS * sizeof(float));
    float* mse_partial = (float*)((char*)d_ws + 2 * NBLOCKS * sizeof(float));

    pair_kernel<<<NBLOCKS, BLK, 0, stream>>>(pred, targ, rank_partial, cnt_partial,
                                             mse_partial);
    finalize_kernel<<<1, BLK, 0, stream>>>(rank_partial, cnt_partial, mse_partial,
                                           (float*)d_out);
}